// Round 1
// baseline (1136.282 us; speedup 1.0000x reference)
//
#include <hip/hip_runtime.h>
#include <hip/hip_bf16.h>
#include <math.h>

#define N_NODES 50000
#define N_EDGES 1200000
#define N_GRAPHS 128
#define D_IN 32
#define D_H 64
#define D_OUT 10

#define EPS 1e-7f
#define MAX_NORM (1.0f - 1e-5f)

// ---------------- wave helpers ----------------

__device__ __forceinline__ float wave_reduce_sum(float v) {
    // full 64-lane butterfly reduction
    #pragma unroll
    for (int off = 32; off > 0; off >>= 1)
        v += __shfl_xor(v, off, 64);
    return v;
}

// logmap0(proj(expmap0(u))) applied to a lane-distributed vector (one
// component per lane; inactive lanes must pass 0). Replicates the
// reference's exact sequence: three separate norm computations, since
// atanh near MAX_NORM is extremely sensitive (d/dx ~ 5e4).
__device__ __forceinline__ float exp_proj_log(float m) {
    // expmap0
    float n = fmaxf(sqrtf(wave_reduce_sum(m * m)), EPS);
    float v = tanhf(n) * m / n;
    // proj
    float nv = fmaxf(sqrtf(wave_reduce_sum(v * v)), EPS);
    if (nv > MAX_NORM) v = v * (MAX_NORM / nv);
    // logmap0
    float nl = sqrtf(wave_reduce_sum(v * v));
    nl = fminf(fmaxf(nl, EPS), MAX_NORM);
    return atanhf(nl) * v / nl;
}

// ---------------- kernels ----------------

// per-edge degree count into cnt[N_NODES]
__global__ void count_kernel(const int* __restrict__ dst, float* __restrict__ cnt, int E) {
    int e = blockIdx.x * 256 + threadIdx.x;
    if (e < E) {
        int d = dst[e];
        d = min(max(d, 0), N_NODES - 1);   // defensive clamp
        atomicAdd(&cnt[d], 1.0f);
    }
}

// u0 = logmap0(proj(expmap0(x))), x: [N, 32]. One wave per node.
__global__ void tangent0_kernel(const float* __restrict__ x, float* __restrict__ u0, int n) {
    int gid = blockIdx.x * 256 + threadIdx.x;
    int node = gid >> 6;
    int lane = gid & 63;
    if (node >= n) return;
    float m = (lane < D_IN) ? x[node * D_IN + lane] : 0.0f;
    float t = exp_proj_log(m);
    if (lane < D_IN) u0[node * D_IN + lane] = t;
}

// t[n,64] = u[n,K] @ W[K,64] + b[64]; block = 256 threads = 4 rows x 64 cols
template <int K>
__global__ void linear_kernel(const float* __restrict__ u, const float* __restrict__ W,
                              const float* __restrict__ b, float* __restrict__ t, int n) {
    __shared__ float Ws[K * 64];
    __shared__ float rows[4][K];
    int tid = threadIdx.x;
    for (int i = tid; i < K * 64; i += 256) Ws[i] = W[i];
    int row0 = blockIdx.x * 4;
    for (int i = tid; i < 4 * K; i += 256) {
        int rr = i / K, kk = i % K;
        int node = row0 + rr;
        rows[rr][kk] = (node < n) ? u[node * K + kk] : 0.0f;
    }
    __syncthreads();
    int r = tid >> 6;
    int j = tid & 63;
    int node = row0 + r;
    if (node < n) {
        float acc = b[j];
        #pragma unroll
        for (int k = 0; k < K; ++k)
            acc = fmaf(rows[r][k], Ws[k * 64 + j], acc);
        t[node * 64 + j] = acc;
    }
}

// one wave per edge; lane i handles feature dim i
__global__ void scatter_kernel(const float* __restrict__ t, const int* __restrict__ src,
                               const int* __restrict__ dst, float* __restrict__ agg, int E) {
    int gid = blockIdx.x * 256 + threadIdx.x;
    int e = gid >> 6;
    int lane = gid & 63;
    if (e >= E) return;
    int s = src[e];
    int d = dst[e];
    s = min(max(s, 0), N_NODES - 1);   // defensive clamp
    d = min(max(d, 0), N_NODES - 1);
    float v = t[s * 64 + lane];
    atomicAdd(&agg[d * 64 + lane], v);
}

// mean -> (leaky_relu) -> expmap0 -> proj -> logmap0; one wave per node
__global__ void finalize_kernel(const float* __restrict__ agg, const float* __restrict__ cnt,
                                float* __restrict__ u, int n, int act) {
    int gid = blockIdx.x * 256 + threadIdx.x;
    int node = gid >> 6;
    int lane = gid & 63;
    if (node >= n) return;
    float m = agg[node * 64 + lane] / fmaxf(cnt[node], 1.0f);
    if (act) m = (m >= 0.0f) ? m : 0.2f * m;
    u[node * 64 + lane] = exp_proj_log(m);
}

// segment-mean pooling over sorted batch ids; each wave handles 8 nodes with
// run-length local accumulation (batch is sorted -> ~8x fewer atomics)
__global__ void pool_kernel(const float* __restrict__ u, const int* __restrict__ batch,
                            float* __restrict__ pooled, float* __restrict__ cntg, int n) {
    int wid = (blockIdx.x * 256 + threadIdx.x) >> 6;
    int lane = threadIdx.x & 63;
    int base = wid * 8;
    if (base >= n) return;
    int curg = min(max(batch[base], 0), N_GRAPHS - 1);
    float acc = 0.0f, c = 0.0f;
    for (int i = 0; i < 8; ++i) {
        int node = base + i;
        if (node >= n) break;
        int g = min(max(batch[node], 0), N_GRAPHS - 1);
        if (g != curg) {
            atomicAdd(&pooled[curg * 64 + lane], acc);
            if (lane == 0) atomicAdd(&cntg[curg], c);
            acc = 0.0f; c = 0.0f; curg = g;
        }
        acc += u[node * 64 + lane];
        c += 1.0f;
    }
    atomicAdd(&pooled[curg * 64 + lane], acc);
    if (lane == 0) atomicAdd(&cntg[curg], c);
}

// final head: mean -> exp/proj/log -> @Wl + bl -> expmap0 -> proj
// one wave (block of 64) per graph
__global__ void head_kernel(const float* __restrict__ pooled, const float* __restrict__ cntg,
                            const float* __restrict__ Wl, const float* __restrict__ bl,
                            float* __restrict__ out) {
    int g = blockIdx.x;
    int lane = threadIdx.x;
    float m = pooled[g * 64 + lane] / fmaxf(cntg[g], 1.0f);
    float z = exp_proj_log(m);
    float acc = 0.0f;
    #pragma unroll
    for (int k = 0; k < 64; ++k) {
        float zk = __shfl(z, k, 64);
        if (lane < D_OUT) acc = fmaf(zk, Wl[k * D_OUT + lane], acc);
    }
    float o = (lane < D_OUT) ? (acc + bl[lane]) : 0.0f;
    // expmap0
    float n = fmaxf(sqrtf(wave_reduce_sum(o * o)), EPS);
    float v = tanhf(n) * o / n;
    // proj
    float nv = fmaxf(sqrtf(wave_reduce_sum(v * v)), EPS);
    if (nv > MAX_NORM) v = v * (MAX_NORM / nv);
    if (lane < D_OUT) out[g * D_OUT + lane] = v;
}

// ---------------- launch ----------------

extern "C" void kernel_launch(void* const* d_in, const int* in_sizes, int n_in,
                              void* d_out, int out_size, void* d_ws, size_t ws_size,
                              hipStream_t stream) {
    const float* x   = (const float*)d_in[0];
    const int* edge  = (const int*)d_in[1];   // [2, E]: src = edge[0:E), dst = edge[E:2E)
    const int* batch = (const int*)d_in[2];
    const float* W1  = (const float*)d_in[3];
    const float* b1  = (const float*)d_in[4];
    const float* W2  = (const float*)d_in[5];
    const float* b2  = (const float*)d_in[6];
    const float* W3  = (const float*)d_in[7];
    const float* b3  = (const float*)d_in[8];
    const float* Wl  = (const float*)d_in[9];
    const float* bl  = (const float*)d_in[10];
    float* out = (float*)d_out;

    const int N = N_NODES, E = N_EDGES, G = N_GRAPHS;
    const int* src = edge;
    const int* dst = edge + E;

    // workspace layout (floats): agg | cnt | pooled | cntg | u | t
    float* ws     = (float*)d_ws;
    float* agg    = ws;                       // N*64
    float* cnt    = agg + (size_t)N * 64;     // N
    float* pooled = cnt + N;                  // G*64
    float* cntg   = pooled + (size_t)G * 64;  // G
    float* u      = cntg + G;                 // N*64
    float* t      = u + (size_t)N * 64;       // N*64

    size_t zero_bytes = ((size_t)N * 64 + N + (size_t)G * 64 + G) * sizeof(float);
    hipMemsetAsync(d_ws, 0, zero_bytes, stream);

    int blocksE   = (E + 255) / 256;           // 1 thread / edge
    int blocksE64 = (E * 64) / 256;            // 1 wave / edge (E*64 divisible by 256)
    int blocksN64 = (N * 64 + 255) / 256;      // 1 wave / node
    int blocksLin = (N + 3) / 4;               // 4 rows / block
    int poolWaves = (N + 7) / 8;
    int blocksPool = (poolWaves * 64 + 255) / 256;

    count_kernel<<<blocksE, 256, 0, stream>>>(dst, cnt, E);
    tangent0_kernel<<<blocksN64, 256, 0, stream>>>(x, u, N);

    // layer 1
    linear_kernel<D_IN><<<blocksLin, 256, 0, stream>>>(u, W1, b1, t, N);
    scatter_kernel<<<blocksE64, 256, 0, stream>>>(t, src, dst, agg, E);
    finalize_kernel<<<blocksN64, 256, 0, stream>>>(agg, cnt, u, N, 1);

    // layer 2
    hipMemsetAsync(agg, 0, (size_t)N * 64 * sizeof(float), stream);
    linear_kernel<D_H><<<blocksLin, 256, 0, stream>>>(u, W2, b2, t, N);
    scatter_kernel<<<blocksE64, 256, 0, stream>>>(t, src, dst, agg, E);
    finalize_kernel<<<blocksN64, 256, 0, stream>>>(agg, cnt, u, N, 1);

    // layer 3 (no activation)
    hipMemsetAsync(agg, 0, (size_t)N * 64 * sizeof(float), stream);
    linear_kernel<D_H><<<blocksLin, 256, 0, stream>>>(u, W3, b3, t, N);
    scatter_kernel<<<blocksE64, 256, 0, stream>>>(t, src, dst, agg, E);
    finalize_kernel<<<blocksN64, 256, 0, stream>>>(agg, cnt, u, N, 0);

    // pooling + head
    pool_kernel<<<blocksPool, 256, 0, stream>>>(u, batch, pooled, cntg, N);
    head_kernel<<<G, 64, 0, stream>>>(pooled, cntg, Wl, bl, out);
}

// Round 2
// 455.965 us; speedup vs baseline: 2.4920x; 2.4920x over previous
//
#include <hip/hip_runtime.h>
#include <hip/hip_bf16.h>
#include <math.h>

#define N_NODES 50000
#define N_EDGES 1200000
#define N_GRAPHS 128
#define D_IN 32
#define D_H 64
#define D_OUT 10
#define ELL_CAP 64

#define EPS 1e-7f
#define MAX_NORM (1.0f - 1e-5f)

// ---------------- wave helpers ----------------

__device__ __forceinline__ float wave_reduce_sum(float v) {
    #pragma unroll
    for (int off = 32; off > 0; off >>= 1)
        v += __shfl_xor(v, off, 64);
    return v;
}

// logmap0(proj(expmap0(u))) on a lane-distributed vector (one component per
// lane; inactive lanes pass 0). Replicates the reference's exact sequence.
__device__ __forceinline__ float exp_proj_log(float m) {
    float n = fmaxf(sqrtf(wave_reduce_sum(m * m)), EPS);
    float v = tanhf(n) * m / n;
    float nv = fmaxf(sqrtf(wave_reduce_sum(v * v)), EPS);
    if (nv > MAX_NORM) v = v * (MAX_NORM / nv);
    float nl = sqrtf(wave_reduce_sum(v * v));
    nl = fminf(fmaxf(nl, EPS), MAX_NORM);
    return atanhf(nl) * v / nl;
}

// ---------------- kernels ----------------

// Build ELL adjacency: for each edge e, append src[e] to dst[e]'s row.
// deg must be zeroed before. deg ends as the true in-degree.
__global__ void ell_fill_kernel(const int* __restrict__ src, const int* __restrict__ dst,
                                int* __restrict__ deg, int* __restrict__ ell, int E) {
    int e = blockIdx.x * 256 + threadIdx.x;
    if (e >= E) return;
    int s = src[e];
    int d = dst[e];
    s = min(max(s, 0), N_NODES - 1);
    d = min(max(d, 0), N_NODES - 1);
    int pos = atomicAdd(&deg[d], 1);
    if (pos < ELL_CAP) ell[d * ELL_CAP + pos] = s;
}

// u0 = logmap0(proj(expmap0(x))), x: [N, 32]. One wave per node.
__global__ void tangent0_kernel(const float* __restrict__ x, float* __restrict__ u0, int n) {
    int gid = blockIdx.x * 256 + threadIdx.x;
    int node = gid >> 6;
    int lane = gid & 63;
    if (node >= n) return;
    float m = (lane < D_IN) ? x[node * D_IN + lane] : 0.0f;
    float t = exp_proj_log(m);
    if (lane < D_IN) u0[node * D_IN + lane] = t;
}

// t[n,64] = u[n,K] @ W[K,64] + b[64]; block = 256 threads = 4 rows x 64 cols
template <int K>
__global__ void linear_kernel(const float* __restrict__ u, const float* __restrict__ W,
                              const float* __restrict__ b, float* __restrict__ t, int n) {
    __shared__ float Ws[K * 64];
    __shared__ float rows[4][K];
    int tid = threadIdx.x;
    for (int i = tid; i < K * 64; i += 256) Ws[i] = W[i];
    int row0 = blockIdx.x * 4;
    for (int i = tid; i < 4 * K; i += 256) {
        int rr = i / K, kk = i % K;
        int node = row0 + rr;
        rows[rr][kk] = (node < n) ? u[node * K + kk] : 0.0f;
    }
    __syncthreads();
    int r = tid >> 6;
    int j = tid & 63;
    int node = row0 + r;
    if (node < n) {
        float acc = b[j];
        #pragma unroll
        for (int k = 0; k < K; ++k)
            acc = fmaf(rows[r][k], Ws[k * 64 + j], acc);
        t[node * 64 + j] = acc;
    }
}

// Fused: gather-mean over ELL neighbors -> (leaky_relu) -> expmap0 -> proj
// -> logmap0. One wave per node, lane = feature dim.
__global__ void agg_finalize_kernel(const float* __restrict__ t, const int* __restrict__ deg,
                                    const int* __restrict__ ell, float* __restrict__ u,
                                    int n, int act) {
    int gid = blockIdx.x * 256 + threadIdx.x;
    int node = gid >> 6;
    int lane = gid & 63;
    if (node >= n) return;
    int d_true = deg[node];
    int d = min(d_true, ELL_CAP);
    // one coalesced load: lane e holds neighbor id e
    int id = (lane < d) ? ell[node * ELL_CAP + lane] : 0;
    float acc = 0.0f;
    int e = 0;
    for (; e + 4 <= d; e += 4) {
        int s0 = __shfl(id, e, 64);
        int s1 = __shfl(id, e + 1, 64);
        int s2 = __shfl(id, e + 2, 64);
        int s3 = __shfl(id, e + 3, 64);
        float v0 = t[s0 * 64 + lane];
        float v1 = t[s1 * 64 + lane];
        float v2 = t[s2 * 64 + lane];
        float v3 = t[s3 * 64 + lane];
        acc += v0 + v1 + v2 + v3;
    }
    for (; e < d; ++e) {
        int s = __shfl(id, e, 64);
        acc += t[s * 64 + lane];
    }
    float m = acc / fmaxf((float)d_true, 1.0f);
    if (act) m = (m >= 0.0f) ? m : 0.2f * m;
    u[node * 64 + lane] = exp_proj_log(m);
}

// segment-mean pooling over sorted batch ids; each wave handles 8 nodes with
// run-length local accumulation
__global__ void pool_kernel(const float* __restrict__ u, const int* __restrict__ batch,
                            float* __restrict__ pooled, float* __restrict__ cntg, int n) {
    int wid = (blockIdx.x * 256 + threadIdx.x) >> 6;
    int lane = threadIdx.x & 63;
    int base = wid * 8;
    if (base >= n) return;
    int curg = min(max(batch[base], 0), N_GRAPHS - 1);
    float acc = 0.0f, c = 0.0f;
    for (int i = 0; i < 8; ++i) {
        int node = base + i;
        if (node >= n) break;
        int g = min(max(batch[node], 0), N_GRAPHS - 1);
        if (g != curg) {
            atomicAdd(&pooled[curg * 64 + lane], acc);
            if (lane == 0) atomicAdd(&cntg[curg], c);
            acc = 0.0f; c = 0.0f; curg = g;
        }
        acc += u[node * 64 + lane];
        c += 1.0f;
    }
    atomicAdd(&pooled[curg * 64 + lane], acc);
    if (lane == 0) atomicAdd(&cntg[curg], c);
}

// final head: mean -> exp/proj/log -> @Wl + bl -> expmap0 -> proj
__global__ void head_kernel(const float* __restrict__ pooled, const float* __restrict__ cntg,
                            const float* __restrict__ Wl, const float* __restrict__ bl,
                            float* __restrict__ out) {
    int g = blockIdx.x;
    int lane = threadIdx.x;
    float m = pooled[g * 64 + lane] / fmaxf(cntg[g], 1.0f);
    float z = exp_proj_log(m);
    float acc = 0.0f;
    #pragma unroll
    for (int k = 0; k < 64; ++k) {
        float zk = __shfl(z, k, 64);
        if (lane < D_OUT) acc = fmaf(zk, Wl[k * D_OUT + lane], acc);
    }
    float o = (lane < D_OUT) ? (acc + bl[lane]) : 0.0f;
    float n = fmaxf(sqrtf(wave_reduce_sum(o * o)), EPS);
    float v = tanhf(n) * o / n;
    float nv = fmaxf(sqrtf(wave_reduce_sum(v * v)), EPS);
    if (nv > MAX_NORM) v = v * (MAX_NORM / nv);
    if (lane < D_OUT) out[g * D_OUT + lane] = v;
}

// ---------------- launch ----------------

extern "C" void kernel_launch(void* const* d_in, const int* in_sizes, int n_in,
                              void* d_out, int out_size, void* d_ws, size_t ws_size,
                              hipStream_t stream) {
    const float* x   = (const float*)d_in[0];
    const int* edge  = (const int*)d_in[1];   // [2, E]
    const int* batch = (const int*)d_in[2];
    const float* W1  = (const float*)d_in[3];
    const float* b1  = (const float*)d_in[4];
    const float* W2  = (const float*)d_in[5];
    const float* b2  = (const float*)d_in[6];
    const float* W3  = (const float*)d_in[7];
    const float* b3  = (const float*)d_in[8];
    const float* Wl  = (const float*)d_in[9];
    const float* bl  = (const float*)d_in[10];
    float* out = (float*)d_out;

    const int N = N_NODES, E = N_EDGES, G = N_GRAPHS;
    const int* src = edge;
    const int* dst = edge + E;

    // workspace layout: [deg:int N][pooled:f G*64][cntg:f G] | [ell:int N*64][u:f N*64][t:f N*64]
    char* ws = (char*)d_ws;
    int*   deg    = (int*)ws;
    float* pooled = (float*)(deg + N);
    float* cntg   = pooled + (size_t)G * 64;
    int*   ell    = (int*)(cntg + G);
    float* u      = (float*)(ell + (size_t)N * ELL_CAP);
    float* t      = u + (size_t)N * 64;

    size_t zero_bytes = ((size_t)N + (size_t)G * 64 + G) * 4;
    hipMemsetAsync(d_ws, 0, zero_bytes, stream);

    int blocksE   = (E + 255) / 256;
    int blocksN64 = (N * 64 + 255) / 256;
    int blocksLin = (N + 3) / 4;
    int poolWaves = (N + 7) / 8;
    int blocksPool = (poolWaves * 64 + 255) / 256;

    ell_fill_kernel<<<blocksE, 256, 0, stream>>>(src, dst, deg, ell, E);
    tangent0_kernel<<<blocksN64, 256, 0, stream>>>(x, u, N);

    // layer 1
    linear_kernel<D_IN><<<blocksLin, 256, 0, stream>>>(u, W1, b1, t, N);
    agg_finalize_kernel<<<blocksN64, 256, 0, stream>>>(t, deg, ell, u, N, 1);

    // layer 2
    linear_kernel<D_H><<<blocksLin, 256, 0, stream>>>(u, W2, b2, t, N);
    agg_finalize_kernel<<<blocksN64, 256, 0, stream>>>(t, deg, ell, u, N, 1);

    // layer 3 (no activation)
    linear_kernel<D_H><<<blocksLin, 256, 0, stream>>>(u, W3, b3, t, N);
    agg_finalize_kernel<<<blocksN64, 256, 0, stream>>>(t, deg, ell, u, N, 0);

    // pooling + head
    pool_kernel<<<blocksPool, 256, 0, stream>>>(u, batch, pooled, cntg, N);
    head_kernel<<<G, 64, 0, stream>>>(pooled, cntg, Wl, bl, out);
}